// Round 2
// baseline (2188.162 us; speedup 1.0000x reference)
//
#include <hip/hip_runtime.h>
#include <hip/hip_bf16.h>

#define B_SZ 8
#define T_SZ 2048
#define NT (B_SZ*T_SZ)      // 16384 tokens
#define DM 256
#define EDIM 512

typedef __hip_bfloat16 bf16;

__device__ __forceinline__ float us2f(unsigned short u){
  unsigned int x = ((unsigned int)u) << 16; float f; __builtin_memcpy(&f,&x,4); return f;
}
__device__ __forceinline__ float b2f(bf16 v){ return __bfloat162float(v); }
__device__ __forceinline__ bf16 f2b(float f){ return __float2bfloat16(f); }

// flag: 1 = inputs are bf16, 0 = inputs are fp32
__device__ __forceinline__ float ld1(const void* p, size_t i, int bf){
  return bf ? us2f(((const unsigned short*)p)[i]) : ((const float*)p)[i];
}
// i must be a multiple of 4
__device__ __forceinline__ void ld4(const void* p, size_t i, int bf, float o[4]){
  if (bf){
    ushort4 v = *(const ushort4*)((const unsigned short*)p + i);
    o[0]=us2f(v.x); o[1]=us2f(v.y); o[2]=us2f(v.z); o[3]=us2f(v.w);
  } else {
    float4 v = *(const float4*)((const float*)p + i);
    o[0]=v.x; o[1]=v.y; o[2]=v.z; o[3]=v.w;
  }
}

// ---------------- dtype detection ----------------
__global__ void k_detect(const void* __restrict__ x, int* __restrict__ flag){
  if (threadIdx.x==0 && blockIdx.x==0){
    const unsigned short* u = (const unsigned short*)x;
    int big=0;
    for (int i=0;i<256;i++){
      float v = us2f(u[i]);
      if (!(v>-64.f && v<64.f)) big++;   // catches NaN/Inf too
    }
    *flag = (big < 8) ? 1 : 0;
  }
}

// block-wide sum for 256-thread blocks (4 waves of 64)
__device__ __forceinline__ float blk_sum256(float v, float* sm){
  #pragma unroll
  for (int m=1;m<64;m<<=1) v += __shfl_xor(v,m);
  int w = threadIdx.x>>6, ln = threadIdx.x&63;
  __syncthreads();
  if (ln==0) sm[w]=v;
  __syncthreads();
  return sm[0]+sm[1]+sm[2]+sm[3];
}

// ---------------- input projection + layernorm ----------------
__global__ __launch_bounds__(256) void k_input_ln(
    const void* __restrict__ x, const void* __restrict__ W,
    const void* __restrict__ bias, const void* __restrict__ g,
    const void* __restrict__ be, const int* __restrict__ flagp,
    bf16* __restrict__ h)
{
  __shared__ float sm[4];
  int bf = *flagp;
  int tok = blockIdx.x, d = threadIdx.x;
  float xr[8], wr[8];
  ld4(x, (size_t)tok*8,   bf, xr);  ld4(x, (size_t)tok*8+4, bf, xr+4);
  ld4(W, (size_t)d*8,     bf, wr);  ld4(W, (size_t)d*8+4,   bf, wr+4);
  float v = ld1(bias, d, bf);
  #pragma unroll
  for (int i=0;i<8;i++) v += xr[i]*wr[i];
  float s1 = blk_sum256(v, sm);
  float m = s1 * (1.f/256.f);
  float c = v - m;
  float s2 = blk_sum256(c*c, sm);
  float inv = rsqrtf(s2*(1.f/256.f) + 1e-5f);
  h[(size_t)tok*DM + d] = f2b(c*inv*ld1(g,d,bf) + ld1(be,d,bf));
}

// ---------------- rmsnorm h -> u ----------------
__global__ __launch_bounds__(256) void k_rms(
    const bf16* __restrict__ h, const void* __restrict__ w, int layer,
    const int* __restrict__ flagp, bf16* __restrict__ u)
{
  __shared__ float sm[4];
  int bf = *flagp;
  int tok = blockIdx.x, d = threadIdx.x;
  float v = b2f(h[(size_t)tok*DM+d]);
  float s = blk_sum256(v*v, sm);
  float inv = rsqrtf(s*(1.f/256.f)+1e-5f);
  u[(size_t)tok*DM+d] = f2b(v*inv*ld1(w, (size_t)layer*DM + d, bf));
}

// ---------------- tiled GEMM: C[M,N] (+)= A[M,K](lda,bf16) * W[N,K]^T, C bf16 ----------------
template<int ACCUM>
__global__ __launch_bounds__(256) void k_gemm(
    const bf16* __restrict__ A, int lda,
    const void* __restrict__ W, size_t Woff, const int* __restrict__ flagp,
    bf16* __restrict__ C, int ldc, int K)
{
  __shared__ float As[16][64];
  __shared__ float Bs[16][64];
  int bf = *flagp;
  int bm = blockIdx.y*64, bn = blockIdx.x*64;
  int tid = threadIdx.x;
  int tx = tid & 15, ty = tid >> 4;
  float acc[4][4] = {};
  int mload = tid >> 2;          // 0..63
  int kload = (tid & 3) * 4;     // 0,4,8,12
  for (int k0=0; k0<K; k0+=16) {
    ushort4 va = *(const ushort4*)((const unsigned short*)A + (size_t)(bm+mload)*lda + k0 + kload);
    As[kload+0][mload]=us2f(va.x); As[kload+1][mload]=us2f(va.y);
    As[kload+2][mload]=us2f(va.z); As[kload+3][mload]=us2f(va.w);
    float wv[4];
    ld4(W, Woff + (size_t)(bn+mload)*K + k0 + kload, bf, wv);
    Bs[kload+0][mload]=wv[0]; Bs[kload+1][mload]=wv[1];
    Bs[kload+2][mload]=wv[2]; Bs[kload+3][mload]=wv[3];
    __syncthreads();
    #pragma unroll
    for (int kk=0;kk<16;kk++){
      float a0[4], b0[4];
      #pragma unroll
      for (int r=0;r<4;r++) a0[r]=As[kk][ty*4+r];
      #pragma unroll
      for (int c=0;c<4;c++) b0[c]=Bs[kk][tx*4+c];
      #pragma unroll
      for (int r=0;r<4;r++)
        #pragma unroll
        for (int c=0;c<4;c++)
          acc[r][c] += a0[r]*b0[c];
    }
    __syncthreads();
  }
  #pragma unroll
  for (int r=0;r<4;r++){
    size_t m = (size_t)(bm + ty*4 + r);
    #pragma unroll
    for (int c=0;c<4;c++){
      size_t idx = m*ldc + bn + tx*4 + c;
      float v = acc[r][c] + (ACCUM ? b2f(C[idx]) : 0.f);
      C[idx] = f2b(v);
    }
  }
}

// ---------------- causal depthwise conv(4) + bias + silu ----------------
__global__ __launch_bounds__(256) void k_conv(
    const bf16* __restrict__ xz, const void* __restrict__ Wc,
    const void* __restrict__ bc, int layer, const int* __restrict__ flagp,
    bf16* __restrict__ xc)
{
  int bf = *flagp;
  int idx = blockIdx.x*256 + threadIdx.x;       // NT*512 total
  int e = idx & 511;
  int tok = idx >> 9;
  int t = tok & (T_SZ-1);
  float w[4];
  ld4(Wc, (size_t)layer*EDIM*4 + (size_t)e*4, bf, w);
  float acc = ld1(bc, (size_t)layer*EDIM + e, bf);
  const bf16* base = xz + (size_t)tok*1024 + e;
  if (t>=3) acc += b2f(base[-3*1024])*w[0];
  if (t>=2) acc += b2f(base[-2*1024])*w[1];
  if (t>=1) acc += b2f(base[-1*1024])*w[2];
  acc += b2f(base[0])*w[3];
  float sig = 1.f/(1.f+__expf(-acc));
  xc[(size_t)tok*EDIM+e] = f2b(acc*sig);
}

// ---------------- dbc[NT,48] = xc[NT,512] * Wx[48,512]^T (fp32 out) ----------------
__global__ __launch_bounds__(64) void k_dbc(
    const bf16* __restrict__ xc, const void* __restrict__ Wx, int layer,
    const int* __restrict__ flagp, float* __restrict__ dbc)
{
  __shared__ float s[512];
  int bf = *flagp;
  int tok = blockIdx.x, tid = threadIdx.x;
  const bf16* row = xc + (size_t)tok*EDIM;
  #pragma unroll
  for (int i=0;i<2;i++){
    int j = tid + i*64;                       // ushort4 index, covers 512 elems
    ushort4 v = ((const ushort4*)row)[j];
    s[j*4+0]=us2f(v.x); s[j*4+1]=us2f(v.y); s[j*4+2]=us2f(v.z); s[j*4+3]=us2f(v.w);
  }
  __syncthreads();
  if (tid < 48) {
    size_t wbase = (size_t)layer*48*EDIM + (size_t)tid*EDIM;
    float acc = 0.f;
    #pragma unroll 8
    for (int j0=0;j0<512;j0+=4){
      float wv[4]; ld4(Wx, wbase + j0, bf, wv);
      acc += s[j0]*wv[0] + s[j0+1]*wv[1] + s[j0+2]*wv[2] + s[j0+3]*wv[3];
    }
    dbc[(size_t)tok*48 + tid] = acc;
  }
}

// ---------------- delta = softplus(dt*Wdt^T + bdt), in-place over xm half of xz ----------------
__global__ __launch_bounds__(512) void k_delta(
    const float* __restrict__ dbc, const void* __restrict__ Wdt,
    const void* __restrict__ bdt, int layer, const int* __restrict__ flagp,
    bf16* __restrict__ xz)
{
  __shared__ float dt[16];
  int bf = *flagp;
  int tok = blockIdx.x, e = threadIdx.x;
  if (e < 16) dt[e] = dbc[(size_t)tok*48 + e];
  __syncthreads();
  float acc = ld1(bdt, (size_t)layer*EDIM + e, bf);
  #pragma unroll
  for (int r0=0;r0<16;r0+=4){
    float wv[4]; ld4(Wdt, (size_t)layer*EDIM*16 + (size_t)e*16 + r0, bf, wv);
    acc += dt[r0]*wv[0] + dt[r0+1]*wv[1] + dt[r0+2]*wv[2] + dt[r0+3]*wv[3];
  }
  float sp = (acc > 20.f) ? acc : log1pf(__expf(acc));
  xz[(size_t)tok*1024 + e] = f2b(sp);
}

// ---------------- selective scan: thread per (b,e,n); y over delta slot ----------------
__global__ __launch_bounds__(256) void k_scan(
    const bf16* __restrict__ xc, const float* __restrict__ dbc,
    bf16* __restrict__ xz, const void* __restrict__ A_log,
    const void* __restrict__ Dsk, int layer, const int* __restrict__ flagp)
{
  int bf = *flagp;
  int blk = blockIdx.x;                 // 256 blocks: b(8) x e-tile(32)
  int b = blk >> 5;
  int e = ((blk & 31) << 4) + (threadIdx.x >> 4);
  int n = threadIdx.x & 15;
  float A  = -__expf(ld1(A_log, (size_t)layer*EDIM*16 + (size_t)e*16 + n, bf));
  float Dp = ld1(Dsk, (size_t)layer*EDIM + e, bf);
  float hst = 0.f;
  size_t tok0 = (size_t)b * T_SZ;
  const int U = 8;
  for (int t0=0; t0<T_SZ; t0+=U) {
    float dl[U], xv[U], zv[U], Bv[U], Cv[U];
    #pragma unroll
    for (int j=0;j<U;j++){
      size_t tok = tok0 + t0 + j;
      dl[j] = b2f(xz[tok*1024 + e]);
      zv[j] = b2f(xz[tok*1024 + 512 + e]);
      xv[j] = b2f(xc[tok*EDIM + e]);
      Bv[j] = dbc[tok*48 + 16 + n];
      Cv[j] = dbc[tok*48 + 32 + n];
    }
    #pragma unroll
    for (int j=0;j<U;j++){
      float dA = __expf(dl[j]*A);
      hst = dA*hst + dl[j]*xv[j]*Bv[j];
      float p = hst*Cv[j];
      p += __shfl_xor(p,1); p += __shfl_xor(p,2);
      p += __shfl_xor(p,4); p += __shfl_xor(p,8);
      if (n==0){
        float z = zv[j];
        float sig = 1.f/(1.f+__expf(-z));
        float y = p + Dp*xv[j];
        xz[(tok0+t0+j)*1024 + e] = f2b(y*(z*sig));
      }
    }
  }
}

// ---------------- final rmsnorm + head + clip + passthrough add ----------------
__global__ __launch_bounds__(256) void k_head(
    const bf16* __restrict__ h, const void* __restrict__ g,
    const void* __restrict__ hW, const void* __restrict__ hb,
    const void* __restrict__ x, const int* __restrict__ flagp,
    void* __restrict__ out)
{
  __shared__ float sm[4];
  int bf = *flagp;
  int tok = blockIdx.x, d = threadIdx.x;
  float v = b2f(h[(size_t)tok*DM+d]);
  float vg = v*ld1(g,d,bf);
  float s0 = blk_sum256(v*v, sm);
  float s1 = blk_sum256(vg*ld1(hW,d,bf), sm);
  float s2 = blk_sum256(vg*ld1(hW,(size_t)DM+d,bf), sm);
  if (d==0){
    float scale = rsqrtf(s0*(1.f/256.f)+1e-5f);
    float d0 = s1*scale + ld1(hb,0,bf);
    float d1 = s2*scale + ld1(hb,1,bf);
    d0 = fminf(fmaxf(d0,-0.005f),0.005f);
    d1 = fminf(fmaxf(d1,-0.0001f),0.0001f);
    float o0 = ld1(x,(size_t)tok*8+4,bf) + d0;
    float o1 = ld1(x,(size_t)tok*8+7,bf) + d1;
    if (bf){
      ((bf16*)out)[tok]      = f2b(o0);
      ((bf16*)out)[NT + tok] = f2b(o1);
    } else {
      ((float*)out)[tok]      = o0;
      ((float*)out)[NT + tok] = o1;
    }
  }
}

extern "C" void kernel_launch(void* const* d_in, const int* in_sizes, int n_in,
                              void* d_out, int out_size, void* d_ws, size_t ws_size,
                              hipStream_t stream)
{
  const void* x      = d_in[0];
  const void* ipW    = d_in[1];
  const void* ipb    = d_in[2];
  const void* ln_g   = d_in[3];
  const void* ln_b   = d_in[4];
  const void* inW    = d_in[5];
  const void* convW  = d_in[6];
  const void* convb  = d_in[7];
  const void* xpW    = d_in[8];
  const void* dtW    = d_in[9];
  const void* dtb    = d_in[10];
  const void* Alog   = d_in[11];
  const void* Dsk    = d_in[12];
  const void* outW   = d_in[13];
  const void* mixw   = d_in[14];
  const void* finw   = d_in[15];
  const void* headW  = d_in[16];
  const void* headb  = d_in[17];

  // ws layout (~59 MiB): [flag 256B][h bf16 8MB][xz bf16 32MB][xc bf16 16MB][dbc f32 3MB]
  char* ws = (char*)d_ws;
  int*  flag   = (int*)ws;
  bf16* h_buf  = (bf16*)(ws + 256);
  bf16* xz_buf = h_buf + (size_t)NT*DM;
  bf16* xc_buf = xz_buf + (size_t)NT*1024;
  bf16* u_buf  = xc_buf;                       // overlay: u dead before conv writes xc
  float* dbc_buf = (float*)(xc_buf + (size_t)NT*EDIM);

  k_detect<<<1,64,0,stream>>>(x, flag);
  k_input_ln<<<NT,256,0,stream>>>(x, ipW, ipb, ln_g, ln_b, flag, h_buf);
  for (int l=0;l<2;l++){
    k_rms<<<NT,256,0,stream>>>(h_buf, mixw, l, flag, u_buf);
    k_gemm<0><<<dim3(1024/64, NT/64),256,0,stream>>>(u_buf, DM, inW, (size_t)l*1024*DM, flag, xz_buf, 1024, DM);
    k_conv<<<(NT*512)/256,256,0,stream>>>(xz_buf, convW, convb, l, flag, xc_buf);
    k_dbc<<<NT,64,0,stream>>>(xc_buf, xpW, l, flag, dbc_buf);
    k_delta<<<NT,512,0,stream>>>(dbc_buf, dtW, dtb, l, flag, xz_buf);
    k_scan<<<256,256,0,stream>>>(xc_buf, dbc_buf, xz_buf, Alog, Dsk, l, flag);
    k_gemm<1><<<dim3(DM/64, NT/64),256,0,stream>>>(xz_buf, 1024, outW, (size_t)l*DM*EDIM, flag, h_buf, DM, EDIM);
  }
  k_head<<<NT,256,0,stream>>>(h_buf, finw, headW, headb, x, flag, d_out);
}

// Round 3
// 1146.356 us; speedup vs baseline: 1.9088x; 1.9088x over previous
//
#include <hip/hip_runtime.h>
#include <hip/hip_bf16.h>

#define B_SZ 8
#define T_SZ 2048
#define NT (B_SZ*T_SZ)      // 16384 tokens
#define DM 256
#define EDIM 512
#define CHUNK 256
#define NC (T_SZ/CHUNK)     // 8 chunks per sequence

typedef __hip_bfloat16 bf16;
typedef __attribute__((ext_vector_type(8))) short short8;
typedef __attribute__((ext_vector_type(4))) float floatx4;

__device__ __forceinline__ float us2f(unsigned short u){
  unsigned int x = ((unsigned int)u) << 16; float f; __builtin_memcpy(&f,&x,4); return f;
}
__device__ __forceinline__ float b2f(bf16 v){ return __bfloat162float(v); }
__device__ __forceinline__ bf16 f2b(float f){ return __float2bfloat16(f); }
__device__ __forceinline__ unsigned short f2us(float f){
  bf16 h = __float2bfloat16(f); unsigned short u; __builtin_memcpy(&u,&h,2); return u;
}

// flag: 1 = inputs are bf16, 0 = inputs are fp32
__device__ __forceinline__ float ld1(const void* p, size_t i, int bfm){
  return bfm ? us2f(((const unsigned short*)p)[i]) : ((const float*)p)[i];
}
__device__ __forceinline__ void ld4(const void* p, size_t i, int bfm, float o[4]){
  if (bfm){
    ushort4 v = *(const ushort4*)((const unsigned short*)p + i);
    o[0]=us2f(v.x); o[1]=us2f(v.y); o[2]=us2f(v.z); o[3]=us2f(v.w);
  } else {
    float4 v = *(const float4*)((const float*)p + i);
    o[0]=v.x; o[1]=v.y; o[2]=v.z; o[3]=v.w;
  }
}

// ---------------- dtype detection ----------------
__global__ void k_detect(const void* __restrict__ x, int* __restrict__ flag){
  if (threadIdx.x==0 && blockIdx.x==0){
    const unsigned short* u = (const unsigned short*)x;
    int big=0;
    for (int i=0;i<256;i++){
      float v = us2f(u[i]);
      if (!(v>-64.f && v<64.f)) big++;
    }
    *flag = (big < 8) ? 1 : 0;
  }
}

__device__ __forceinline__ float blk_sum256(float v, float* sm){
  #pragma unroll
  for (int m=1;m<64;m<<=1) v += __shfl_xor(v,m);
  int w = threadIdx.x>>6, ln = threadIdx.x&63;
  __syncthreads();
  if (ln==0) sm[w]=v;
  __syncthreads();
  return sm[0]+sm[1]+sm[2]+sm[3];
}

// ---------------- input projection + layernorm ----------------
__global__ __launch_bounds__(256) void k_input_ln(
    const void* __restrict__ x, const void* __restrict__ W,
    const void* __restrict__ bias, const void* __restrict__ g,
    const void* __restrict__ be, const int* __restrict__ flagp,
    bf16* __restrict__ h)
{
  __shared__ float sm[4];
  int bfm = *flagp;
  int tok = blockIdx.x, d = threadIdx.x;
  float xr[8], wr[8];
  ld4(x, (size_t)tok*8,   bfm, xr);  ld4(x, (size_t)tok*8+4, bfm, xr+4);
  ld4(W, (size_t)d*8,     bfm, wr);  ld4(W, (size_t)d*8+4,   bfm, wr+4);
  float v = ld1(bias, d, bfm);
  #pragma unroll
  for (int i=0;i<8;i++) v += xr[i]*wr[i];
  float s1 = blk_sum256(v, sm);
  float m = s1 * (1.f/256.f);
  float c = v - m;
  float s2 = blk_sum256(c*c, sm);
  float inv = rsqrtf(s2*(1.f/256.f) + 1e-5f);
  h[(size_t)tok*DM + d] = f2b(c*inv*ld1(g,d,bfm) + ld1(be,d,bfm));
}

// ---------------- rmsnorm h -> u ----------------
__global__ __launch_bounds__(256) void k_rms(
    const bf16* __restrict__ h, const void* __restrict__ w, int layer,
    const int* __restrict__ flagp, bf16* __restrict__ u)
{
  __shared__ float sm[4];
  int bfm = *flagp;
  int tok = blockIdx.x, d = threadIdx.x;
  float v = b2f(h[(size_t)tok*DM+d]);
  float s = blk_sum256(v*v, sm);
  float inv = rsqrtf(s*(1.f/256.f)+1e-5f);
  u[(size_t)tok*DM+d] = f2b(v*inv*ld1(w, (size_t)layer*DM + d, bfm));
}

// ---------------- MFMA GEMM: C[M,N] (+)= A[M,K](bf16,lda) * W[N,K]^T ----------------
// block 256 thr = 4 waves; tile 64x64; K-step 32; LDS stride 40 (2-way conflicts only)
template<int ACCUM>
__global__ __launch_bounds__(256) void k_gemm_mfma(
    const bf16* __restrict__ A, int lda,
    const void* __restrict__ W, size_t Woff, const int* __restrict__ flagp,
    bf16* __restrict__ C, int ldc, int K)
{
  __shared__ unsigned short As[64*40];
  __shared__ unsigned short Bs[64*40];
  int isbf = *flagp;
  int tid = threadIdx.x;
  int bm = blockIdx.y*64, bn = blockIdx.x*64;
  int row = tid>>2, kc = (tid&3)*8;
  int lane = tid&63, wv = tid>>6, cl = lane&15, quad = lane>>4;
  floatx4 acc[4] = {{0,0,0,0},{0,0,0,0},{0,0,0,0},{0,0,0,0}};
  for (int k0=0; k0<K; k0+=32){
    // stage A tile (always bf16)
    short8 va = *(const short8*)((const short*)A + (size_t)(bm+row)*lda + k0 + kc);
    *(short8*)&As[row*40+kc] = va;
    // stage W tile
    if (isbf){
      short8 vw = *(const short8*)((const short*)W + Woff + (size_t)(bn+row)*K + k0 + kc);
      *(short8*)&Bs[row*40+kc] = vw;
    } else {
      const float* wp = (const float*)W + Woff + (size_t)(bn+row)*K + k0 + kc;
      float4 w0 = *(const float4*)wp;
      float4 w1 = *(const float4*)(wp+4);
      unsigned short* dst = &Bs[row*40+kc];
      dst[0]=f2us(w0.x); dst[1]=f2us(w0.y); dst[2]=f2us(w0.z); dst[3]=f2us(w0.w);
      dst[4]=f2us(w1.x); dst[5]=f2us(w1.y); dst[6]=f2us(w1.z); dst[7]=f2us(w1.w);
    }
    __syncthreads();
    short8 af = *(const short8*)&As[(wv*16+cl)*40 + quad*8];
    #pragma unroll
    for (int nt=0;nt<4;nt++){
      short8 bfr = *(const short8*)&Bs[(nt*16+cl)*40 + quad*8];
      acc[nt] = __builtin_amdgcn_mfma_f32_16x16x32_bf16(af, bfr, acc[nt], 0,0,0);
    }
    __syncthreads();
  }
  // C/D layout: col=lane&15, row=quad*4+reg
  #pragma unroll
  for (int nt=0;nt<4;nt++){
    #pragma unroll
    for (int r=0;r<4;r++){
      size_t rowg = (size_t)(bm + wv*16 + quad*4 + r);
      size_t idx = rowg*ldc + bn + nt*16 + cl;
      float v = acc[nt][r] + (ACCUM ? b2f(C[idx]) : 0.f);
      C[idx] = f2b(v);
    }
  }
}

// ---------------- causal depthwise conv(4) + bias + silu ----------------
__global__ __launch_bounds__(256) void k_conv(
    const bf16* __restrict__ xz, const void* __restrict__ Wc,
    const void* __restrict__ bc, int layer, const int* __restrict__ flagp,
    bf16* __restrict__ xc)
{
  int bfm = *flagp;
  int idx = blockIdx.x*256 + threadIdx.x;       // NT*512 total
  int e = idx & 511;
  int tok = idx >> 9;
  int t = tok & (T_SZ-1);
  float w[4];
  ld4(Wc, (size_t)layer*EDIM*4 + (size_t)e*4, bfm, w);
  float acc = ld1(bc, (size_t)layer*EDIM + e, bfm);
  const bf16* base = xz + (size_t)tok*1024 + e;
  if (t>=3) acc += b2f(base[-3*1024])*w[0];
  if (t>=2) acc += b2f(base[-2*1024])*w[1];
  if (t>=1) acc += b2f(base[-1*1024])*w[2];
  acc += b2f(base[0])*w[3];
  float sig = 1.f/(1.f+__expf(-acc));
  xc[(size_t)tok*EDIM+e] = f2b(acc*sig);
}

// ---------------- dbc[NT,48] = xc[NT,512] * Wx[48,512]^T (fp32 out) ----------------
__global__ __launch_bounds__(64) void k_dbc(
    const bf16* __restrict__ xc, const void* __restrict__ Wx, int layer,
    const int* __restrict__ flagp, float* __restrict__ dbc)
{
  __shared__ float s[512];
  int bfm = *flagp;
  int tok = blockIdx.x, tid = threadIdx.x;
  const bf16* row = xc + (size_t)tok*EDIM;
  #pragma unroll
  for (int i=0;i<2;i++){
    int j = tid + i*64;
    ushort4 v = ((const ushort4*)row)[j];
    s[j*4+0]=us2f(v.x); s[j*4+1]=us2f(v.y); s[j*4+2]=us2f(v.z); s[j*4+3]=us2f(v.w);
  }
  __syncthreads();
  if (tid < 48) {
    size_t wbase = (size_t)layer*48*EDIM + (size_t)tid*EDIM;
    float acc = 0.f;
    #pragma unroll 8
    for (int j0=0;j0<512;j0+=4){
      float wv[4]; ld4(Wx, wbase + j0, bfm, wv);
      acc += s[j0]*wv[0] + s[j0+1]*wv[1] + s[j0+2]*wv[2] + s[j0+3]*wv[3];
    }
    dbc[(size_t)tok*48 + tid] = acc;
  }
}

// ---------------- delta = softplus(dt*Wdt^T + bdt), in-place over xm half of xz ----------------
__global__ __launch_bounds__(512) void k_delta(
    const float* __restrict__ dbc, const void* __restrict__ Wdt,
    const void* __restrict__ bdt, int layer, const int* __restrict__ flagp,
    bf16* __restrict__ xz)
{
  __shared__ float dt[16];
  int bfm = *flagp;
  int tok = blockIdx.x, e = threadIdx.x;
  if (e < 16) dt[e] = dbc[(size_t)tok*48 + e];
  __syncthreads();
  float acc = ld1(bdt, (size_t)layer*EDIM + e, bfm);
  #pragma unroll
  for (int r0=0;r0<16;r0+=4){
    float wv[4]; ld4(Wdt, (size_t)layer*EDIM*16 + (size_t)e*16 + r0, bfm, wv);
    acc += dt[r0]*wv[0] + dt[r0+1]*wv[1] + dt[r0+2]*wv[2] + dt[r0+3]*wv[3];
  }
  float sp = (acc > 20.f) ? acc : log1pf(__expf(acc));
  xz[(size_t)tok*1024 + e] = f2b(sp);
}

// ---------------- chunked scan, pass A: per-chunk summaries (no shuffles) ----------------
// block = 16 e x 16 n; grid = b(8) x c(8) x etile(32)
__global__ __launch_bounds__(256) void k_scanA(
    const bf16* __restrict__ xc, const float* __restrict__ dbc,
    const bf16* __restrict__ xz, const void* __restrict__ A_log,
    int layer, const int* __restrict__ flagp,
    float* __restrict__ S, float* __restrict__ P)
{
  int bfm = *flagp;
  int x = blockIdx.x;
  int b = x>>8, c = (x>>5)&7, et = x&31;
  int e = et*16 + (threadIdx.x>>4);
  int n = threadIdx.x&15;
  float A = -__expf(ld1(A_log, (size_t)layer*EDIM*16 + (size_t)e*16 + n, bfm));
  float hst=0.f, sd=0.f;
  size_t tok0 = (size_t)b*T_SZ + (size_t)c*CHUNK;
  for (int t0=0;t0<CHUNK;t0+=8){
    float dl[8], xv[8], Bv[8];
    #pragma unroll
    for (int j=0;j<8;j++){
      size_t tok = tok0 + t0 + j;
      dl[j] = b2f(xz[tok*1024 + e]);
      xv[j] = b2f(xc[tok*EDIM + e]);
      Bv[j] = dbc[tok*48 + 16 + n];
    }
    #pragma unroll
    for (int j=0;j<8;j++){
      float dA = __expf(dl[j]*A);
      hst = dA*hst + dl[j]*xv[j]*Bv[j];
      sd += dl[j];
    }
  }
  size_t o = ((size_t)(b*NC+c)*EDIM + e)*16 + n;
  S[o] = hst;
  P[o] = __expf(A*sd);
}

// ---------------- pass B: serial combine across chunks ----------------
__global__ __launch_bounds__(256) void k_scanB(
    const float* __restrict__ S, const float* __restrict__ P,
    float* __restrict__ Hinit)
{
  int idx = blockIdx.x*256 + threadIdx.x;   // 8*512*16 = 65536
  int n = idx&15, e = (idx>>4)&511, b = idx>>13;
  float h = 0.f;
  #pragma unroll
  for (int c=0;c<NC;c++){
    size_t o = ((size_t)(b*NC+c)*EDIM + e)*16 + n;
    Hinit[o] = h;
    h = P[o]*h + S[o];
  }
}

// ---------------- pass C: re-scan with init, batched-shuffle y reduction ----------------
__global__ __launch_bounds__(256) void k_scanC(
    const bf16* __restrict__ xc, const float* __restrict__ dbc,
    bf16* __restrict__ xz, const void* __restrict__ A_log,
    const void* __restrict__ Dsk, int layer, const int* __restrict__ flagp,
    const float* __restrict__ Hinit)
{
  int bfm = *flagp;
  int x = blockIdx.x;
  int b = x>>8, c = (x>>5)&7, et = x&31;
  int e = et*16 + (threadIdx.x>>4);
  int n = threadIdx.x&15;
  float A  = -__expf(ld1(A_log, (size_t)layer*EDIM*16 + (size_t)e*16 + n, bfm));
  float Dp = ld1(Dsk, (size_t)layer*EDIM + e, bfm);
  size_t o = ((size_t)(b*NC+c)*EDIM + e)*16 + n;
  float hst = Hinit[o];
  size_t tok0 = (size_t)b*T_SZ + (size_t)c*CHUNK;
  for (int t0=0;t0<CHUNK;t0+=8){
    float dl[8], xv[8], zv[8], Bv[8], Cv[8], p[8];
    #pragma unroll
    for (int j=0;j<8;j++){
      size_t tok = tok0 + t0 + j;
      dl[j] = b2f(xz[tok*1024 + e]);
      zv[j] = b2f(xz[tok*1024 + 512 + e]);
      xv[j] = b2f(xc[tok*EDIM + e]);
      Bv[j] = dbc[tok*48 + 16 + n];
      Cv[j] = dbc[tok*48 + 32 + n];
    }
    #pragma unroll
    for (int j=0;j<8;j++){
      float dA = __expf(dl[j]*A);
      hst = dA*hst + dl[j]*xv[j]*Bv[j];
      p[j] = hst*Cv[j];
    }
    // level-major shuffle reduce over 16-lane groups: independent per j -> pipelined
    #pragma unroll
    for (int j=0;j<8;j++) p[j] += __shfl_xor(p[j],1);
    #pragma unroll
    for (int j=0;j<8;j++) p[j] += __shfl_xor(p[j],2);
    #pragma unroll
    for (int j=0;j<8;j++) p[j] += __shfl_xor(p[j],4);
    #pragma unroll
    for (int j=0;j<8;j++) p[j] += __shfl_xor(p[j],8);
    if (n==0){
      #pragma unroll
      for (int j=0;j<8;j++){
        float z = zv[j];
        float sig = 1.f/(1.f+__expf(-z));
        float y = p[j] + Dp*xv[j];
        xz[(tok0+t0+j)*1024 + e] = f2b(y*(z*sig));
      }
    }
  }
}

// ---------------- final rmsnorm + head + clip + passthrough add ----------------
__global__ __launch_bounds__(256) void k_head(
    const bf16* __restrict__ h, const void* __restrict__ g,
    const void* __restrict__ hW, const void* __restrict__ hb,
    const void* __restrict__ x, const int* __restrict__ flagp,
    void* __restrict__ out)
{
  __shared__ float sm[4];
  int bfm = *flagp;
  int tok = blockIdx.x, d = threadIdx.x;
  float v = b2f(h[(size_t)tok*DM+d]);
  float vg = v*ld1(g,d,bfm);
  float s0 = blk_sum256(v*v, sm);
  float s1 = blk_sum256(vg*ld1(hW,d,bfm), sm);
  float s2 = blk_sum256(vg*ld1(hW,(size_t)DM+d,bfm), sm);
  if (d==0){
    float scale = rsqrtf(s0*(1.f/256.f)+1e-5f);
    float d0 = s1*scale + ld1(hb,0,bfm);
    float d1 = s2*scale + ld1(hb,1,bfm);
    d0 = fminf(fmaxf(d0,-0.005f),0.005f);
    d1 = fminf(fmaxf(d1,-0.0001f),0.0001f);
    float o0 = ld1(x,(size_t)tok*8+4,bfm) + d0;
    float o1 = ld1(x,(size_t)tok*8+7,bfm) + d1;
    if (bfm){
      ((bf16*)out)[tok]      = f2b(o0);
      ((bf16*)out)[NT + tok] = f2b(o1);
    } else {
      ((float*)out)[tok]      = o0;
      ((float*)out)[NT + tok] = o1;
    }
  }
}

extern "C" void kernel_launch(void* const* d_in, const int* in_sizes, int n_in,
                              void* d_out, int out_size, void* d_ws, size_t ws_size,
                              hipStream_t stream)
{
  const void* x      = d_in[0];
  const void* ipW    = d_in[1];
  const void* ipb    = d_in[2];
  const void* ln_g   = d_in[3];
  const void* ln_b   = d_in[4];
  const void* inW    = d_in[5];
  const void* convW  = d_in[6];
  const void* convb  = d_in[7];
  const void* xpW    = d_in[8];
  const void* dtW    = d_in[9];
  const void* dtb    = d_in[10];
  const void* Alog   = d_in[11];
  const void* Dsk    = d_in[12];
  const void* outW   = d_in[13];
  const void* mixw   = d_in[14];
  const void* finw   = d_in[15];
  const void* headW  = d_in[16];
  const void* headb  = d_in[17];

  // ws (~65 MiB): flag | h bf16 8M | xz bf16 32M | xc bf16 16M | dbc f32 3M | S,P,Hinit f32 2M each
  char* ws = (char*)d_ws;
  int*  flag   = (int*)ws;
  bf16* h_buf  = (bf16*)(ws + 256);
  bf16* xz_buf = h_buf + (size_t)NT*DM;
  bf16* xc_buf = xz_buf + (size_t)NT*1024;
  bf16* u_buf  = xc_buf;                       // overlay: u dead before conv writes xc
  float* dbc_buf = (float*)(xc_buf + (size_t)NT*EDIM);
  float* S_buf = dbc_buf + (size_t)NT*48;
  float* P_buf = S_buf + (size_t)B_SZ*NC*EDIM*16;
  float* H_buf = P_buf + (size_t)B_SZ*NC*EDIM*16;

  k_detect<<<1,64,0,stream>>>(x, flag);
  k_input_ln<<<NT,256,0,stream>>>(x, ipW, ipb, ln_g, ln_b, flag, h_buf);
  for (int l=0;l<2;l++){
    k_rms<<<NT,256,0,stream>>>(h_buf, mixw, l, flag, u_buf);
    k_gemm_mfma<0><<<dim3(1024/64, NT/64),256,0,stream>>>(u_buf, DM, inW, (size_t)l*1024*DM, flag, xz_buf, 1024, DM);
    k_conv<<<(NT*512)/256,256,0,stream>>>(xz_buf, convW, convb, l, flag, xc_buf);
    k_dbc<<<NT,64,0,stream>>>(xc_buf, xpW, l, flag, dbc_buf);
    k_delta<<<NT,512,0,stream>>>(dbc_buf, dtW, dtb, l, flag, xz_buf);
    k_scanA<<<B_SZ*NC*32,256,0,stream>>>(xc_buf, dbc_buf, xz_buf, Alog, l, flag, S_buf, P_buf);
    k_scanB<<<256,256,0,stream>>>(S_buf, P_buf, H_buf);
    k_scanC<<<B_SZ*NC*32,256,0,stream>>>(xc_buf, dbc_buf, xz_buf, Alog, Dsk, l, flag, H_buf);
    k_gemm_mfma<1><<<dim3(DM/64, NT/64),256,0,stream>>>(xz_buf, 1024, outW, (size_t)l*DM*EDIM, flag, h_buf, DM, EDIM);
  }
  k_head<<<NT,256,0,stream>>>(h_buf, finw, headW, headb, x, flag, d_out);
}

// Round 4
// 830.041 us; speedup vs baseline: 2.6362x; 1.3811x over previous
//
#include <hip/hip_runtime.h>
#include <hip/hip_bf16.h>

#define B_SZ 8
#define T_SZ 2048
#define NT (B_SZ*T_SZ)      // 16384 tokens
#define DM 256
#define EDIM 512
#define CHUNK 256
#define NC (T_SZ/CHUNK)     // 8 chunks per sequence

typedef __hip_bfloat16 bf16;
typedef __attribute__((ext_vector_type(8))) short short8;
typedef __attribute__((ext_vector_type(4))) float floatx4;

__device__ __forceinline__ float us2f(unsigned short u){
  unsigned int x = ((unsigned int)u) << 16; float f; __builtin_memcpy(&f,&x,4); return f;
}
__device__ __forceinline__ float b2f(bf16 v){ return __bfloat162float(v); }
__device__ __forceinline__ bf16 f2b(float f){ return __float2bfloat16(f); }
__device__ __forceinline__ unsigned short f2us(float f){
  bf16 h = __float2bfloat16(f); unsigned short u; __builtin_memcpy(&u,&h,2); return u;
}

// flag: 1 = inputs are bf16, 0 = inputs are fp32
__device__ __forceinline__ float ld1(const void* p, size_t i, int bfm){
  return bfm ? us2f(((const unsigned short*)p)[i]) : ((const float*)p)[i];
}
__device__ __forceinline__ void ld4(const void* p, size_t i, int bfm, float o[4]){
  if (bfm){
    ushort4 v = *(const ushort4*)((const unsigned short*)p + i);
    o[0]=us2f(v.x); o[1]=us2f(v.y); o[2]=us2f(v.z); o[3]=us2f(v.w);
  } else {
    float4 v = *(const float4*)((const float*)p + i);
    o[0]=v.x; o[1]=v.y; o[2]=v.z; o[3]=v.w;
  }
}
// load 8 input elems as bf16 fragment (handles fp32->bf16 conversion)
__device__ __forceinline__ short8 ld8frag(const void* p, size_t i, int bfm){
  if (bfm) return *(const short8*)((const short*)p + i);
  const float* wp = (const float*)p + i;
  float4 w0 = *(const float4*)wp;
  float4 w1 = *(const float4*)(wp+4);
  short tmp[8];
  tmp[0]=(short)f2us(w0.x); tmp[1]=(short)f2us(w0.y); tmp[2]=(short)f2us(w0.z); tmp[3]=(short)f2us(w0.w);
  tmp[4]=(short)f2us(w1.x); tmp[5]=(short)f2us(w1.y); tmp[6]=(short)f2us(w1.z); tmp[7]=(short)f2us(w1.w);
  return *(short8*)tmp;
}

// ---------------- dtype detection ----------------
__global__ void k_detect(const void* __restrict__ x, int* __restrict__ flag){
  if (threadIdx.x==0 && blockIdx.x==0){
    const unsigned short* u = (const unsigned short*)x;
    int big=0;
    for (int i=0;i<256;i++){
      float v = us2f(u[i]);
      if (!(v>-64.f && v<64.f)) big++;
    }
    *flag = (big < 8) ? 1 : 0;
  }
}

__device__ __forceinline__ float blk_sum256(float v, float* sm){
  #pragma unroll
  for (int m=1;m<64;m<<=1) v += __shfl_xor(v,m);
  int w = threadIdx.x>>6, ln = threadIdx.x&63;
  __syncthreads();
  if (ln==0) sm[w]=v;
  __syncthreads();
  return sm[0]+sm[1]+sm[2]+sm[3];
}

// ---------------- input projection + layernorm ----------------
__global__ __launch_bounds__(256) void k_input_ln(
    const void* __restrict__ x, const void* __restrict__ W,
    const void* __restrict__ bias, const void* __restrict__ g,
    const void* __restrict__ be, const int* __restrict__ flagp,
    bf16* __restrict__ h)
{
  __shared__ float sm[4];
  int bfm = *flagp;
  int tok = blockIdx.x, d = threadIdx.x;
  float xr[8], wr[8];
  ld4(x, (size_t)tok*8,   bfm, xr);  ld4(x, (size_t)tok*8+4, bfm, xr+4);
  ld4(W, (size_t)d*8,     bfm, wr);  ld4(W, (size_t)d*8+4,   bfm, wr+4);
  float v = ld1(bias, d, bfm);
  #pragma unroll
  for (int i=0;i<8;i++) v += xr[i]*wr[i];
  float s1 = blk_sum256(v, sm);
  float m = s1 * (1.f/256.f);
  float c = v - m;
  float s2 = blk_sum256(c*c, sm);
  float inv = rsqrtf(s2*(1.f/256.f) + 1e-5f);
  h[(size_t)tok*DM + d] = f2b(c*inv*ld1(g,d,bfm) + ld1(be,d,bfm));
}

// ---------------- rmsnorm h -> u ----------------
__global__ __launch_bounds__(256) void k_rms(
    const bf16* __restrict__ h, const void* __restrict__ w, int layer,
    const int* __restrict__ flagp, bf16* __restrict__ u)
{
  __shared__ float sm[4];
  int bfm = *flagp;
  int tok = blockIdx.x, d = threadIdx.x;
  float v = b2f(h[(size_t)tok*DM+d]);
  float s = blk_sum256(v*v, sm);
  float inv = rsqrtf(s*(1.f/256.f)+1e-5f);
  u[(size_t)tok*DM+d] = f2b(v*inv*ld1(w, (size_t)layer*DM + d, bfm));
}

// ---------------- MFMA GEMM: C[M,N] (+)= A[M,K](bf16,lda) * W[N,K]^T ----------------
template<int ACCUM>
__global__ __launch_bounds__(256) void k_gemm_mfma(
    const bf16* __restrict__ A, int lda,
    const void* __restrict__ W, size_t Woff, const int* __restrict__ flagp,
    bf16* __restrict__ C, int ldc, int K)
{
  __shared__ unsigned short As[64*40];
  __shared__ unsigned short Bs[64*40];
  int isbf = *flagp;
  int tid = threadIdx.x;
  int bm = blockIdx.y*64, bn = blockIdx.x*64;
  int row = tid>>2, kc = (tid&3)*8;
  int lane = tid&63, wv = tid>>6, cl = lane&15, quad = lane>>4;
  floatx4 acc[4] = {{0,0,0,0},{0,0,0,0},{0,0,0,0},{0,0,0,0}};
  for (int k0=0; k0<K; k0+=32){
    short8 va = *(const short8*)((const short*)A + (size_t)(bm+row)*lda + k0 + kc);
    *(short8*)&As[row*40+kc] = va;
    *(short8*)&Bs[row*40+kc] = ld8frag(W, Woff + (size_t)(bn+row)*K + k0 + kc, isbf);
    __syncthreads();
    short8 af = *(const short8*)&As[(wv*16+cl)*40 + quad*8];
    #pragma unroll
    for (int nt=0;nt<4;nt++){
      short8 bfr = *(const short8*)&Bs[(nt*16+cl)*40 + quad*8];
      acc[nt] = __builtin_amdgcn_mfma_f32_16x16x32_bf16(af, bfr, acc[nt], 0,0,0);
    }
    __syncthreads();
  }
  // C/D layout: col=lane&15, row=quad*4+reg
  #pragma unroll
  for (int nt=0;nt<4;nt++){
    #pragma unroll
    for (int r=0;r<4;r++){
      size_t rowg = (size_t)(bm + wv*16 + quad*4 + r);
      size_t idx = rowg*ldc + bn + nt*16 + cl;
      float v = acc[nt][r] + (ACCUM ? b2f(C[idx]) : 0.f);
      C[idx] = f2b(v);
    }
  }
}

// ---------------- causal depthwise conv(4) + bias + silu ----------------
__global__ __launch_bounds__(256) void k_conv(
    const bf16* __restrict__ xz, const void* __restrict__ Wc,
    const void* __restrict__ bc, int layer, const int* __restrict__ flagp,
    bf16* __restrict__ xc)
{
  int bfm = *flagp;
  int idx = blockIdx.x*256 + threadIdx.x;       // NT*512 total
  int e = idx & 511;
  int tok = idx >> 9;
  int t = tok & (T_SZ-1);
  float w[4];
  ld4(Wc, (size_t)layer*EDIM*4 + (size_t)e*4, bfm, w);
  float acc = ld1(bc, (size_t)layer*EDIM + e, bfm);
  const bf16* base = xz + (size_t)tok*1024 + e;
  if (t>=3) acc += b2f(base[-3*1024])*w[0];
  if (t>=2) acc += b2f(base[-2*1024])*w[1];
  if (t>=1) acc += b2f(base[-1*1024])*w[2];
  acc += b2f(base[0])*w[3];
  float sig = 1.f/(1.f+__expf(-acc));
  xc[(size_t)tok*EDIM+e] = f2b(acc*sig);
}

// ---------------- dbc[NT,48] = xc[NT,512] * Wx[48,512]^T via MFMA, no LDS ----------------
// 256 thr = 4 waves; wave w owns rows bm+w*16..+15, all 3 n-tiles; K=512 in 16 steps
__global__ __launch_bounds__(256) void k_dbc_mfma(
    const bf16* __restrict__ xc, const void* __restrict__ Wx, int layer,
    const int* __restrict__ flagp, float* __restrict__ dbc)
{
  int isbf = *flagp;
  int lane = threadIdx.x & 63, wv = threadIdx.x >> 6;
  int cl = lane & 15, quad = lane >> 4;
  int m0 = blockIdx.x*64 + wv*16;
  floatx4 acc[3] = {{0,0,0,0},{0,0,0,0},{0,0,0,0}};
  const short* A = (const short*)xc;
  size_t wbase = (size_t)layer*48*EDIM;
  #pragma unroll 4
  for (int k0=0;k0<EDIM;k0+=32){
    short8 af = *(const short8*)(A + (size_t)(m0+cl)*EDIM + k0 + quad*8);
    #pragma unroll
    for (int nt=0;nt<3;nt++){
      short8 bfr = ld8frag(Wx, wbase + (size_t)(nt*16+cl)*EDIM + k0 + quad*8, isbf);
      acc[nt] = __builtin_amdgcn_mfma_f32_16x16x32_bf16(af, bfr, acc[nt], 0,0,0);
    }
  }
  // C/D: row = quad*4+r, col = cl
  #pragma unroll
  for (int nt=0;nt<3;nt++)
    #pragma unroll
    for (int r=0;r<4;r++)
      dbc[(size_t)(m0+quad*4+r)*48 + nt*16 + cl] = acc[nt][r];
}

// ---------------- delta = softplus(dt*Wdt^T + bdt), in-place over xm half of xz ----------------
__global__ __launch_bounds__(512) void k_delta(
    const float* __restrict__ dbc, const void* __restrict__ Wdt,
    const void* __restrict__ bdt, int layer, const int* __restrict__ flagp,
    bf16* __restrict__ xz)
{
  __shared__ float dt[16];
  int bfm = *flagp;
  int tok = blockIdx.x, e = threadIdx.x;
  if (e < 16) dt[e] = dbc[(size_t)tok*48 + e];
  __syncthreads();
  float acc = ld1(bdt, (size_t)layer*EDIM + e, bfm);
  #pragma unroll
  for (int r0=0;r0<16;r0+=4){
    float wv[4]; ld4(Wdt, (size_t)layer*EDIM*16 + (size_t)e*16 + r0, bfm, wv);
    acc += dt[r0]*wv[0] + dt[r0+1]*wv[1] + dt[r0+2]*wv[2] + dt[r0+3]*wv[3];
  }
  float sp = (acc > 20.f) ? acc : log1pf(__expf(acc));
  xz[(size_t)tok*1024 + e] = f2b(sp);
}

// ---------------- chunked scan, pass A: per-chunk summaries (no shuffles) ----------------
__global__ __launch_bounds__(256) void k_scanA(
    const bf16* __restrict__ xc, const float* __restrict__ dbc,
    const bf16* __restrict__ xz, const void* __restrict__ A_log,
    int layer, const int* __restrict__ flagp,
    float* __restrict__ S, float* __restrict__ P)
{
  int bfm = *flagp;
  int x = blockIdx.x;
  int b = x>>8, c = (x>>5)&7, et = x&31;
  int e = et*16 + (threadIdx.x>>4);
  int n = threadIdx.x&15;
  float A = -__expf(ld1(A_log, (size_t)layer*EDIM*16 + (size_t)e*16 + n, bfm));
  float hst=0.f, sd=0.f;
  size_t tok0 = (size_t)b*T_SZ + (size_t)c*CHUNK;
  for (int t0=0;t0<CHUNK;t0+=8){
    float dl[8], xv[8], Bv[8];
    #pragma unroll
    for (int j=0;j<8;j++){
      size_t tok = tok0 + t0 + j;
      dl[j] = b2f(xz[tok*1024 + e]);
      xv[j] = b2f(xc[tok*EDIM + e]);
      Bv[j] = dbc[tok*48 + 16 + n];
    }
    #pragma unroll
    for (int j=0;j<8;j++){
      float dA = __expf(dl[j]*A);
      hst = dA*hst + dl[j]*xv[j]*Bv[j];
      sd += dl[j];
    }
  }
  size_t o = ((size_t)(b*NC+c)*EDIM + e)*16 + n;
  S[o] = hst;
  P[o] = __expf(A*sd);
}

// ---------------- pass B: serial combine across chunks ----------------
__global__ __launch_bounds__(256) void k_scanB(
    const float* __restrict__ S, const float* __restrict__ P,
    float* __restrict__ Hinit)
{
  int idx = blockIdx.x*256 + threadIdx.x;   // 8*512*16 = 65536
  int n = idx&15, e = (idx>>4)&511, b = idx>>13;
  float h = 0.f;
  #pragma unroll
  for (int c=0;c<NC;c++){
    size_t o = ((size_t)(b*NC+c)*EDIM + e)*16 + n;
    Hinit[o] = h;
    h = P[o]*h + S[o];
  }
}

// ---------------- pass C: re-scan with init, batched-shuffle y reduction ----------------
__global__ __launch_bounds__(256) void k_scanC(
    const bf16* __restrict__ xc, const float* __restrict__ dbc,
    bf16* __restrict__ xz, const void* __restrict__ A_log,
    const void* __restrict__ Dsk, int layer, const int* __restrict__ flagp,
    const float* __restrict__ Hinit)
{
  int bfm = *flagp;
  int x = blockIdx.x;
  int b = x>>8, c = (x>>5)&7, et = x&31;
  int e = et*16 + (threadIdx.x>>4);
  int n = threadIdx.x&15;
  float A  = -__expf(ld1(A_log, (size_t)layer*EDIM*16 + (size_t)e*16 + n, bfm));
  float Dp = ld1(Dsk, (size_t)layer*EDIM + e, bfm);
  size_t o = ((size_t)(b*NC+c)*EDIM + e)*16 + n;
  float hst = Hinit[o];
  size_t tok0 = (size_t)b*T_SZ + (size_t)c*CHUNK;
  for (int t0=0;t0<CHUNK;t0+=8){
    float dl[8], xv[8], zv[8], Bv[8], Cv[8], p[8];
    #pragma unroll
    for (int j=0;j<8;j++){
      size_t tok = tok0 + t0 + j;
      dl[j] = b2f(xz[tok*1024 + e]);
      zv[j] = b2f(xz[tok*1024 + 512 + e]);
      xv[j] = b2f(xc[tok*EDIM + e]);
      Bv[j] = dbc[tok*48 + 16 + n];
      Cv[j] = dbc[tok*48 + 32 + n];
    }
    #pragma unroll
    for (int j=0;j<8;j++){
      float dA = __expf(dl[j]*A);
      hst = dA*hst + dl[j]*xv[j]*Bv[j];
      p[j] = hst*Cv[j];
    }
    #pragma unroll
    for (int j=0;j<8;j++) p[j] += __shfl_xor(p[j],1);
    #pragma unroll
    for (int j=0;j<8;j++) p[j] += __shfl_xor(p[j],2);
    #pragma unroll
    for (int j=0;j<8;j++) p[j] += __shfl_xor(p[j],4);
    #pragma unroll
    for (int j=0;j<8;j++) p[j] += __shfl_xor(p[j],8);
    if (n==0){
      #pragma unroll
      for (int j=0;j<8;j++){
        float z = zv[j];
        float sig = 1.f/(1.f+__expf(-z));
        float y = p[j] + Dp*xv[j];
        xz[(tok0+t0+j)*1024 + e] = f2b(y*(z*sig));
      }
    }
  }
}

// ---------------- final rmsnorm + head + clip + passthrough add ----------------
__global__ __launch_bounds__(256) void k_head(
    const bf16* __restrict__ h, const void* __restrict__ g,
    const void* __restrict__ hW, const void* __restrict__ hb,
    const void* __restrict__ x, const int* __restrict__ flagp,
    void* __restrict__ out)
{
  __shared__ float sm[4];
  int bfm = *flagp;
  int tok = blockIdx.x, d = threadIdx.x;
  float v = b2f(h[(size_t)tok*DM+d]);
  float vg = v*ld1(g,d,bfm);
  float s0 = blk_sum256(v*v, sm);
  float s1 = blk_sum256(vg*ld1(hW,d,bfm), sm);
  float s2 = blk_sum256(vg*ld1(hW,(size_t)DM+d,bfm), sm);
  if (d==0){
    float scale = rsqrtf(s0*(1.f/256.f)+1e-5f);
    float d0 = s1*scale + ld1(hb,0,bfm);
    float d1 = s2*scale + ld1(hb,1,bfm);
    d0 = fminf(fmaxf(d0,-0.005f),0.005f);
    d1 = fminf(fmaxf(d1,-0.0001f),0.0001f);
    float o0 = ld1(x,(size_t)tok*8+4,bfm) + d0;
    float o1 = ld1(x,(size_t)tok*8+7,bfm) + d1;
    if (bfm){
      ((bf16*)out)[tok]      = f2b(o0);
      ((bf16*)out)[NT + tok] = f2b(o1);
    } else {
      ((float*)out)[tok]      = o0;
      ((float*)out)[NT + tok] = o1;
    }
  }
}

extern "C" void kernel_launch(void* const* d_in, const int* in_sizes, int n_in,
                              void* d_out, int out_size, void* d_ws, size_t ws_size,
                              hipStream_t stream)
{
  const void* x      = d_in[0];
  const void* ipW    = d_in[1];
  const void* ipb    = d_in[2];
  const void* ln_g   = d_in[3];
  const void* ln_b   = d_in[4];
  const void* inW    = d_in[5];
  const void* convW  = d_in[6];
  const void* convb  = d_in[7];
  const void* xpW    = d_in[8];
  const void* dtW    = d_in[9];
  const void* dtb    = d_in[10];
  const void* Alog   = d_in[11];
  const void* Dsk    = d_in[12];
  const void* outW   = d_in[13];
  const void* mixw   = d_in[14];
  const void* finw   = d_in[15];
  const void* headW  = d_in[16];
  const void* headb  = d_in[17];

  char* ws = (char*)d_ws;
  int*  flag   = (int*)ws;
  bf16* h_buf  = (bf16*)(ws + 256);
  bf16* xz_buf = h_buf + (size_t)NT*DM;
  bf16* xc_buf = xz_buf + (size_t)NT*1024;
  bf16* u_buf  = xc_buf;                       // overlay: u dead before conv writes xc
  float* dbc_buf = (float*)(xc_buf + (size_t)NT*EDIM);
  float* S_buf = dbc_buf + (size_t)NT*48;
  float* P_buf = S_buf + (size_t)B_SZ*NC*EDIM*16;
  float* H_buf = P_buf + (size_t)B_SZ*NC*EDIM*16;

  k_detect<<<1,64,0,stream>>>(x, flag);
  k_input_ln<<<NT,256,0,stream>>>(x, ipW, ipb, ln_g, ln_b, flag, h_buf);
  for (int l=0;l<2;l++){
    k_rms<<<NT,256,0,stream>>>(h_buf, mixw, l, flag, u_buf);
    k_gemm_mfma<0><<<dim3(1024/64, NT/64),256,0,stream>>>(u_buf, DM, inW, (size_t)l*1024*DM, flag, xz_buf, 1024, DM);
    k_conv<<<(NT*512)/256,256,0,stream>>>(xz_buf, convW, convb, l, flag, xc_buf);
    k_dbc_mfma<<<NT/64,256,0,stream>>>(xc_buf, xpW, l, flag, dbc_buf);
    k_delta<<<NT,512,0,stream>>>(dbc_buf, dtW, dtb, l, flag, xz_buf);
    k_scanA<<<B_SZ*NC*32,256,0,stream>>>(xc_buf, dbc_buf, xz_buf, Alog, l, flag, S_buf, P_buf);
    k_scanB<<<256,256,0,stream>>>(S_buf, P_buf, H_buf);
    k_scanC<<<B_SZ*NC*32,256,0,stream>>>(xc_buf, dbc_buf, xz_buf, Alog, Dsk, l, flag, H_buf);
    k_gemm_mfma<1><<<dim3(DM/64, NT/64),256,0,stream>>>(xz_buf, 1024, outW, (size_t)l*DM*EDIM, flag, h_buf, DM, EDIM);
  }
  k_head<<<NT,256,0,stream>>>(h_buf, finw, headW, headb, x, flag, d_out);
}